// Round 2
// baseline (186.082 us; speedup 1.0000x reference)
//
#include <hip/hip_runtime.h>
#include <hip/hip_bf16.h>
#include <math.h>

typedef __bf16 bf16_t;
typedef __bf16 bf16x8 __attribute__((ext_vector_type(8)));
typedef __bf16 bf16x4 __attribute__((ext_vector_type(4)));
typedef float  f32x4  __attribute__((ext_vector_type(4)));

#define NB    8
#define NC    512
#define NHW   1024
#define NHEAD 8
#define NHD   64
#define NG    32
#define NCG   16
#define NO3   1536   // 3*C

// ---- async global->LDS, 16B per lane. LDS dest must be wave-uniform base. ----
__device__ __forceinline__ void lds_load16(bf16_t* lds, const bf16_t* g) {
  __builtin_amdgcn_global_load_lds(
      (__attribute__((address_space(1))) unsigned int*)(g),
      (__attribute__((address_space(3))) unsigned int*)(void*)(lds),
      16, 0, 0);
}

__device__ __forceinline__ float sum16(float v) {
  v += __shfl_xor(v, 1); v += __shfl_xor(v, 2);
  v += __shfl_xor(v, 4); v += __shfl_xor(v, 8);
  return v;
}
__device__ __forceinline__ float max16(float v) {
  v = fmaxf(v, __shfl_xor(v, 1)); v = fmaxf(v, __shfl_xor(v, 2));
  v = fmaxf(v, __shfl_xor(v, 4)); v = fmaxf(v, __shfl_xor(v, 8));
  return v;
}

// =====================================================================
// Kernel 1: GroupNorm. One block per (b,g). Writes xn transposed (B,HW,C) bf16.
// =====================================================================
__global__ __launch_bounds__(256)
void gn_kernel(const float* __restrict__ x, const float* __restrict__ gw,
               const float* __restrict__ gb, bf16_t* __restrict__ xn)
{
  const int bg = blockIdx.x;
  const int b = bg >> 5, g = bg & 31;
  const float* xp = x + ((size_t)b * NC + g * NCG) * NHW;
  const int tid = threadIdx.x;
  const int wave = tid >> 6, lane = tid & 63;

  float s1 = 0.f, s2 = 0.f;
  const float4* xp4 = (const float4*)xp;           // 16*1024/4 = 4096 float4
  for (int i = tid; i < 4096; i += 256) {
    float4 v = xp4[i];
    s1 += v.x + v.y + v.z + v.w;
    s2 += v.x * v.x + v.y * v.y + v.z * v.z + v.w * v.w;
  }
  for (int off = 32; off > 0; off >>= 1) {
    s1 += __shfl_down(s1, off);
    s2 += __shfl_down(s2, off);
  }
  __shared__ float red[16];
  if (lane == 0) { red[wave] = s1; red[8 + wave] = s2; }
  __syncthreads();
  float tot1 = red[0] + red[1] + red[2] + red[3];
  float tot2 = red[8] + red[9] + red[10] + red[11];
  const float mean = tot1 * (1.0f / 16384.0f);
  const float var  = tot2 * (1.0f / 16384.0f) - mean * mean;
  const float rstd = rsqrtf(var + 1e-5f);

  float gam[NCG], bet[NCG];
  #pragma unroll
  for (int c = 0; c < NCG; ++c) {
    gam[c] = gw[g * NCG + c] * rstd;
    bet[c] = gb[g * NCG + c] - mean * gam[c];
  }
  bf16_t* op = xn + (size_t)b * NHW * NC + g * NCG;
  for (int s = tid; s < NHW; s += 256) {
    __align__(16) bf16_t vals[NCG];
    #pragma unroll
    for (int c = 0; c < NCG; ++c)
      vals[c] = (bf16_t)(xp[c * NHW + s] * gam[c] + bet[c]);
    *(bf16x8*)(op + (size_t)s * NC)     = *(const bf16x8*)&vals[0];
    *(bf16x8*)(op + (size_t)s * NC + 8) = *(const bf16x8*)&vals[8];
  }
}

// =====================================================================
// Kernel 2: convert qkv_w (1536x512) and proj_w (512x512) fp32 -> bf16
// =====================================================================
__global__ __launch_bounds__(256)
void wconv_kernel(const float* __restrict__ qw, const float* __restrict__ pw,
                  bf16_t* __restrict__ qwb, bf16_t* __restrict__ pwb)
{
  const int gid = blockIdx.x * 256 + threadIdx.x;   // one float4 each
  const int n1 = NO3 * NC / 4;                      // 196608
  float4 v; bf16x4 o;
  if (gid < n1) {
    v = ((const float4*)qw)[gid];
    o[0] = (bf16_t)v.x; o[1] = (bf16_t)v.y; o[2] = (bf16_t)v.z; o[3] = (bf16_t)v.w;
    ((bf16x4*)qwb)[gid] = o;
  } else {
    int g2 = gid - n1;                              // < 65536
    v = ((const float4*)pw)[g2];
    o[0] = (bf16_t)v.x; o[1] = (bf16_t)v.y; o[2] = (bf16_t)v.z; o[3] = (bf16_t)v.w;
    ((bf16x4*)pwb)[g2] = o;
  }
}

// =====================================================================
// Shared 128x128 (K=512, BK=32) NT main loop: A rows -> D rows, B rows -> D cols.
// LDS layout: row-major (row, k), stride 32 bf16, no pad (global_load_lds constraint).
// =====================================================================
__device__ __forceinline__ void gemm_mainloop(const bf16_t* Ap, const bf16_t* Bp,
                                              bf16_t* sA, bf16_t* sB, f32x4 (&acc)[4][4])
{
  const int tid = threadIdx.x;
  const int wave = tid >> 6, lane = tid & 63;
  const int quad = lane >> 4, l16 = lane & 15;
  const int wm = wave >> 1, wn = wave & 1;
  for (int k0 = 0; k0 < 512; k0 += 32) {
    #pragma unroll
    for (int j = 0; j < 2; ++j) {
      int c = wave * 64 + j * 256 + lane;      // chunk id, 16B each
      int row = c >> 2, ko = (c & 3) * 8;
      lds_load16(sA + (size_t)(wave * 64 + j * 256) * 8, Ap + (size_t)row * 512 + k0 + ko);
      lds_load16(sB + (size_t)(wave * 64 + j * 256) * 8, Bp + (size_t)row * 512 + k0 + ko);
    }
    __syncthreads();
    bf16x8 af[4], bfr[4];
    #pragma unroll
    for (int mi = 0; mi < 4; ++mi)
      af[mi] = *(const bf16x8*)(sA + (wm * 64 + mi * 16 + l16) * 32 + quad * 8);
    #pragma unroll
    for (int ni = 0; ni < 4; ++ni)
      bfr[ni] = *(const bf16x8*)(sB + (wn * 64 + ni * 16 + l16) * 32 + quad * 8);
    #pragma unroll
    for (int mi = 0; mi < 4; ++mi)
      #pragma unroll
      for (int ni = 0; ni < 4; ++ni)
        acc[mi][ni] = __builtin_amdgcn_mfma_f32_16x16x32_bf16(af[mi], bfr[ni], acc[mi][ni], 0, 0, 0);
    __syncthreads();
  }
}

// =====================================================================
// Kernel 3: QKV GEMM.  D[s, o] = xn[b,s,:] . w[o,:]  (M=s=1024, N=o=1536, K=512)
// Epilogue scatters: q,k -> (b,h,s,d) [q scaled by 0.125]; v -> (b,h,d,t) via LDS transpose.
// grid (12, 8, 8) = (o-tile, s-tile, b)
// =====================================================================
__global__ __launch_bounds__(256, 2)
void qkv_gemm(const bf16_t* __restrict__ xn, const bf16_t* __restrict__ w,
              const float* __restrict__ bias,
              bf16_t* __restrict__ qbuf, bf16_t* __restrict__ kbuf, bf16_t* __restrict__ vbuf)
{
  __shared__ __align__(16) bf16_t smem[128 * 136];   // 34816 B; main loop uses first 16 KB
  bf16_t* sA = smem;
  bf16_t* sB = smem + 4096;
  const int tid = threadIdx.x;
  const int wave = tid >> 6, lane = tid & 63;
  const int quad = lane >> 4, l16 = lane & 15;
  const int wm = wave >> 1, wn = wave & 1;
  const int bx = blockIdx.x, by = blockIdx.y, b = blockIdx.z;

  const bf16_t* Ap = xn + ((size_t)b * NHW + by * 128) * NC;  // rows = s
  const bf16_t* Bp = w + (size_t)bx * 128 * NC;               // rows = o
  f32x4 acc[4][4] = {};
  gemm_mainloop(Ap, Bp, sA, sB, acc);

  const int obase = bx * 128 + wn * 64;
  const int sbase = by * 128 + wm * 64;
  float bv[4];
  #pragma unroll
  for (int ni = 0; ni < 4; ++ni) bv[ni] = bias[obase + ni * 16 + l16];

  if (bx < 8) {               // q (bx<4) or k region: o-contiguous layout (b,h,s,d)
    const bool isq = (bx < 4);
    bf16_t* basep = isq ? qbuf : kbuf;
    const float scale = isq ? 0.125f : 1.0f;   // hd^-0.5 folded into q
    #pragma unroll
    for (int ni = 0; ni < 4; ++ni) {
      int o = obase + ni * 16 + l16;
      int hh = (o >> 6) & 7, dd = o & 63;
      bf16_t* dst = basep + ((size_t)(b * NHEAD + hh) * NHW) * NHD + dd;
      #pragma unroll
      for (int mi = 0; mi < 4; ++mi)
        #pragma unroll
        for (int r = 0; r < 4; ++r) {
          int s = sbase + mi * 16 + quad * 4 + r;
          dst[(size_t)s * NHD] = (bf16_t)((acc[mi][ni][r] + bv[ni]) * scale);
        }
    }
  } else {                    // v region: transpose tile via LDS -> (b,h,d,t)
    bf16_t* sC = smem;        // 128 (o) x 136 stride (s)
    __syncthreads();
    #pragma unroll
    for (int ni = 0; ni < 4; ++ni)
      #pragma unroll
      for (int mi = 0; mi < 4; ++mi)
        #pragma unroll
        for (int r = 0; r < 4; ++r)
          sC[(wn * 64 + ni * 16 + l16) * 136 + wm * 64 + mi * 16 + quad * 4 + r] =
              (bf16_t)(acc[mi][ni][r] + bv[ni]);
    __syncthreads();
    int o_local = tid >> 1, shalf = (tid & 1) << 6;
    int ov = (bx - 8) * 128 + o_local;
    int hh = ov >> 6, dd = ov & 63;
    bf16_t* dst = vbuf + ((size_t)(b * NHEAD + hh) * NHD + dd) * NHW + by * 128 + shalf;
    #pragma unroll
    for (int jj = 0; jj < 8; ++jj)
      *(bf16x8*)(dst + jj * 8) = *(const bf16x8*)&sC[o_local * 136 + shalf + jj * 8];
  }
}

// =====================================================================
// Kernel 4: flash attention. grid 1024 = (qt fastest (16), h, b); 4 waves.
// Block q-tile = 64 rows; wave owns 16 q rows. K-tile = 64, 16 iterations.
// LDS 27648 B -> 4+ blocks/CU; __launch_bounds__(256,4) -> 16 waves/CU.
// =====================================================================
__global__ __launch_bounds__(256, 4)
void attn_kernel(const bf16_t* __restrict__ qbuf, const bf16_t* __restrict__ kbuf,
                 const bf16_t* __restrict__ vbuf, bf16_t* __restrict__ obuf)
{
  __shared__ __align__(16) bf16_t Ks[64 * 72];      // (t, d) pad 64->72
  __shared__ __align__(16) bf16_t Vs[64 * 72];      // (d, t) pad 64->72
  __shared__ __align__(16) bf16_t Ps[4][16 * 72];   // per-wave P tile (s, t)

  const int tid = threadIdx.x;
  const int wave = tid >> 6, lane = tid & 63;
  const int quad = lane >> 4, l16 = lane & 15;
  const int idx = blockIdx.x;
  const int qt = idx & 15, h = (idx >> 4) & 7, b = idx >> 7;
  const size_t bh = (size_t)b * NHEAD + h;
  const bf16_t* qp = qbuf + (bh * NHW + qt * 64) * NHD;
  const bf16_t* kp = kbuf + bh * NHW * NHD;
  const bf16_t* vp = vbuf + bh * NHD * NHW;

  // Q A-frags: rows wave*16 + l16, k = d (two K=32 chunks)
  bf16x8 qf[2];
  #pragma unroll
  for (int kc = 0; kc < 2; ++kc)
    qf[kc] = *(const bf16x8*)(qp + (size_t)(wave * 16 + l16) * NHD + kc * 32 + quad * 8);

  float m_i[4], l_i[4];
  f32x4 oacc[4] = {};
  #pragma unroll
  for (int r = 0; r < 4; ++r) { m_i[r] = -1e30f; l_i[r] = 0.f; }

  for (int kt = 0; kt < 16; ++kt) {
    const bf16_t* ksrc = kp + (size_t)kt * 64 * NHD;
    const bf16_t* vsrc = vp + kt * 64;
    #pragma unroll
    for (int j = 0; j < 2; ++j) {              // K tile: 512 16B chunks
      int c = tid + j * 256;
      int t = c >> 3, doff = (c & 7) * 8;
      *(bf16x8*)&Ks[t * 72 + doff] = *(const bf16x8*)(ksrc + (size_t)t * NHD + doff);
    }
    #pragma unroll
    for (int j = 0; j < 2; ++j) {              // V^T tile: 512 16B chunks
      int c = tid + j * 256;
      int d = c >> 3, toff = (c & 7) * 8;
      *(bf16x8*)&Vs[d * 72 + toff] = *(const bf16x8*)(vsrc + (size_t)d * NHW + toff);
    }
    __syncthreads();

    // S = Q K^T  (rows s=16 per wave, cols t=64); scale folded into q
    f32x4 sf[4] = {};
    #pragma unroll
    for (int ni = 0; ni < 4; ++ni) {
      bf16x8 k0 = *(const bf16x8*)&Ks[(ni * 16 + l16) * 72 + quad * 8];
      bf16x8 k1 = *(const bf16x8*)&Ks[(ni * 16 + l16) * 72 + 32 + quad * 8];
      sf[ni] = __builtin_amdgcn_mfma_f32_16x16x32_bf16(qf[0], k0, sf[ni], 0, 0, 0);
      sf[ni] = __builtin_amdgcn_mfma_f32_16x16x32_bf16(qf[1], k1, sf[ni], 0, 0, 0);
    }
    // online softmax (row s = quad*4+r, cols across ni & l16)
    float alpha[4], rs[4];
    #pragma unroll
    for (int r = 0; r < 4; ++r) {
      float mx = fmaxf(fmaxf(sf[0][r], sf[1][r]), fmaxf(sf[2][r], sf[3][r]));
      mx = max16(mx);
      float mnew = fmaxf(m_i[r], mx);
      alpha[r] = __expf(m_i[r] - mnew);
      m_i[r] = mnew;
      rs[r] = 0.f;
    }
    #pragma unroll
    for (int ni = 0; ni < 4; ++ni)
      #pragma unroll
      for (int r = 0; r < 4; ++r) {
        float p = __expf(sf[ni][r] - m_i[r]);
        rs[r] += p;
        Ps[wave][(quad * 4 + r) * 72 + ni * 16 + l16] = (bf16_t)p;
      }
    #pragma unroll
    for (int r = 0; r < 4; ++r)
      l_i[r] = l_i[r] * alpha[r] + sum16(rs[r]);
    #pragma unroll
    for (int ni = 0; ni < 4; ++ni)
      #pragma unroll
      for (int r = 0; r < 4; ++r)
        oacc[ni][r] *= alpha[r];

    // drain wave's own Ps ds_writes before re-reading as A-frags (wave-private region)
    asm volatile("s_waitcnt lgkmcnt(0)" ::: "memory");

    // O += P V  (A = P rows s, B = V^T cols d); k = t, two K=32 chunks
    #pragma unroll
    for (int kc = 0; kc < 2; ++kc) {
      bf16x8 pa = *(const bf16x8*)&Ps[wave][l16 * 72 + kc * 32 + quad * 8];
      #pragma unroll
      for (int ni = 0; ni < 4; ++ni) {
        bf16x8 vf = *(const bf16x8*)&Vs[(ni * 16 + l16) * 72 + kc * 32 + quad * 8];
        oacc[ni] = __builtin_amdgcn_mfma_f32_16x16x32_bf16(pa, vf, oacc[ni], 0, 0, 0);
      }
    }
    __syncthreads();
  }

  // epilogue: O / l -> obuf (b, s, c) bf16, c = h*64 + d
  #pragma unroll
  for (int r = 0; r < 4; ++r) {
    float inv = 1.0f / l_i[r];
    int s = qt * 64 + wave * 16 + quad * 4 + r;
    bf16_t* orow = obuf + ((size_t)b * NHW + s) * NC + h * NHD;
    #pragma unroll
    for (int ni = 0; ni < 4; ++ni)
      orow[ni * 16 + l16] = (bf16_t)(oacc[ni][r] * inv);
  }
}

// =====================================================================
// Kernel 5: proj GEMM + bias + residual. D[co, s] = w[co,:] . ob[b,s,:]
// grid (8, 4, 8) = (s-tile, co-tile, b). fp32 out, coalesced over s.
// =====================================================================
__global__ __launch_bounds__(256, 2)
void proj_gemm(const bf16_t* __restrict__ ob, const bf16_t* __restrict__ w,
               const float* __restrict__ bias, const float* __restrict__ x,
               float* __restrict__ out)
{
  __shared__ __align__(16) bf16_t smem[8192];
  bf16_t* sA = smem;
  bf16_t* sB = smem + 4096;
  const int tid = threadIdx.x;
  const int wave = tid >> 6, lane = tid & 63;
  const int quad = lane >> 4, l16 = lane & 15;
  const int wm = wave >> 1, wn = wave & 1;
  const int bx = blockIdx.x, by = blockIdx.y, b = blockIdx.z;

  const bf16_t* Ap = w + (size_t)by * 128 * NC;               // rows = co
  const bf16_t* Bp = ob + ((size_t)b * NHW + bx * 128) * NC;  // rows = s
  f32x4 acc[4][4] = {};
  gemm_mainloop(Ap, Bp, sA, sB, acc);

  const int cobase = by * 128 + wm * 64;
  const int sbase  = bx * 128 + wn * 64;
  #pragma unroll
  for (int mi = 0; mi < 4; ++mi)
    #pragma unroll
    for (int r = 0; r < 4; ++r) {
      int co = cobase + mi * 16 + quad * 4 + r;
      float pb = bias[co];
      const float* xrow = x + ((size_t)b * NC + co) * NHW;
      float* orow = out + ((size_t)b * NC + co) * NHW;
      #pragma unroll
      for (int ni = 0; ni < 4; ++ni) {
        int s = sbase + ni * 16 + l16;
        orow[s] = acc[mi][ni][r] + pb + xrow[s];
      }
    }
}

// =====================================================================
extern "C" void kernel_launch(void* const* d_in, const int* in_sizes, int n_in,
                              void* d_out, int out_size, void* d_ws, size_t ws_size,
                              hipStream_t stream)
{
  const float* x      = (const float*)d_in[0];
  const float* gn_w   = (const float*)d_in[1];
  const float* gn_b   = (const float*)d_in[2];
  const float* qkv_w  = (const float*)d_in[3];
  const float* qkv_b  = (const float*)d_in[4];
  const float* proj_w = (const float*)d_in[5];
  const float* proj_b = (const float*)d_in[6];
  float* out = (float*)d_out;

  char* ws = (char*)d_ws;
  // xn (B,HW,C) bf16 reused later as attention output obuf (B,HW,C) bf16
  bf16_t* xn   = (bf16_t*)(ws);                       //  8 MiB
  bf16_t* qwb  = (bf16_t*)(ws + 8388608);             //  1.5 MiB (1536x512)
  bf16_t* pwb  = (bf16_t*)(ws + 9961472);             //  0.5 MiB (512x512)
  bf16_t* qbuf = (bf16_t*)(ws + 10485760);            //  8 MiB (b,h,s,d)
  bf16_t* kbuf = (bf16_t*)(ws + 18874368);            //  8 MiB (b,h,s,d)
  bf16_t* vbuf = (bf16_t*)(ws + 27262976);            //  8 MiB (b,h,d,t)
  bf16_t* obuf = xn;                                  // reuse: xn dead after qkv_gemm

  gn_kernel<<<dim3(NB * NG), dim3(256), 0, stream>>>(x, gn_w, gn_b, xn);
  wconv_kernel<<<dim3(1024), dim3(256), 0, stream>>>(qkv_w, proj_w, qwb, pwb);
  qkv_gemm<<<dim3(12, 8, NB), dim3(256), 0, stream>>>(xn, qwb, qkv_b, qbuf, kbuf, vbuf);
  attn_kernel<<<dim3(1024), dim3(256), 0, stream>>>(qbuf, kbuf, vbuf, obuf);
  proj_gemm<<<dim3(8, 4, NB), dim3(256), 0, stream>>>(obuf, pwb, proj_b, x, out);
}

// Round 6
// 172.395 us; speedup vs baseline: 1.0794x; 1.0794x over previous
//
#include <hip/hip_runtime.h>
#include <hip/hip_bf16.h>
#include <math.h>

typedef __bf16 bf16_t;
typedef __bf16 bf16x8 __attribute__((ext_vector_type(8)));
typedef __bf16 bf16x4 __attribute__((ext_vector_type(4)));
typedef float  f32x4  __attribute__((ext_vector_type(4)));
typedef short  short4v __attribute__((ext_vector_type(4)));

#define NB    8
#define NC    512
#define NHW   1024
#define NHEAD 8
#define NHD   64
#define NG    32
#define NCG   16
#define NO3   1536   // 3*C

// ---- async global->LDS, 16B per lane. LDS dest must be wave-uniform base. ----
__device__ __forceinline__ void lds_load16(bf16_t* lds, const bf16_t* g) {
  __builtin_amdgcn_global_load_lds(
      (__attribute__((address_space(1))) unsigned int*)(g),
      (__attribute__((address_space(3))) unsigned int*)(void*)(lds),
      16, 0, 0);
}

// K=16 bf16 MFMA: C/D layout == B layout, which is what makes on-lane P reuse work.
// R4/R5 lesson: no #error anywhere, no defined(__HIP_DEVICE_COMPILE__) (this ROCm
// defines it as 0 on HOST). Host pass: __has_builtin=0 -> asm branch, which is
// only PARSED (never codegen'd for device-only fns) -> always compiles.
// Device pass: amdgcn builtins registered -> clean builtin path.
__device__ __forceinline__ f32x4 mfma16(bf16x4 a, bf16x4 b, f32x4 c) {
#if __has_builtin(__builtin_amdgcn_mfma_f32_16x16x16bf16_1k)
  return __builtin_amdgcn_mfma_f32_16x16x16bf16_1k(
      __builtin_bit_cast(short4v, a), __builtin_bit_cast(short4v, b), c, 0, 0, 0);
#else
  f32x4 d;
  asm("v_mfma_f32_16x16x16_bf16 %0, %1, %2, %3"
      : "=v"(d) : "v"(a), "v"(b), "v"(c));
  return d;
#endif
}

// =====================================================================
// Kernel 1: GroupNorm. One block per (b,g). Writes xn transposed (B,HW,C) bf16.
// =====================================================================
__global__ __launch_bounds__(256)
void gn_kernel(const float* __restrict__ x, const float* __restrict__ gw,
               const float* __restrict__ gb, bf16_t* __restrict__ xn)
{
  const int bg = blockIdx.x;
  const int b = bg >> 5, g = bg & 31;
  const float* xp = x + ((size_t)b * NC + g * NCG) * NHW;
  const int tid = threadIdx.x;
  const int wave = tid >> 6, lane = tid & 63;

  float s1 = 0.f, s2 = 0.f;
  const float4* xp4 = (const float4*)xp;           // 16*1024/4 = 4096 float4
  for (int i = tid; i < 4096; i += 256) {
    float4 v = xp4[i];
    s1 += v.x + v.y + v.z + v.w;
    s2 += v.x * v.x + v.y * v.y + v.z * v.z + v.w * v.w;
  }
  for (int off = 32; off > 0; off >>= 1) {
    s1 += __shfl_down(s1, off);
    s2 += __shfl_down(s2, off);
  }
  __shared__ float red[16];
  if (lane == 0) { red[wave] = s1; red[8 + wave] = s2; }
  __syncthreads();
  float tot1 = red[0] + red[1] + red[2] + red[3];
  float tot2 = red[8] + red[9] + red[10] + red[11];
  const float mean = tot1 * (1.0f / 16384.0f);
  const float var  = tot2 * (1.0f / 16384.0f) - mean * mean;
  const float rstd = rsqrtf(var + 1e-5f);

  float gam[NCG], bet[NCG];
  #pragma unroll
  for (int c = 0; c < NCG; ++c) {
    gam[c] = gw[g * NCG + c] * rstd;
    bet[c] = gb[g * NCG + c] - mean * gam[c];
  }
  bf16_t* op = xn + (size_t)b * NHW * NC + g * NCG;
  for (int s = tid; s < NHW; s += 256) {
    __align__(16) bf16_t vals[NCG];
    #pragma unroll
    for (int c = 0; c < NCG; ++c)
      vals[c] = (bf16_t)(xp[c * NHW + s] * gam[c] + bet[c]);
    *(bf16x8*)(op + (size_t)s * NC)     = *(const bf16x8*)&vals[0];
    *(bf16x8*)(op + (size_t)s * NC + 8) = *(const bf16x8*)&vals[8];
  }
}

// =====================================================================
// Kernel 2: convert qkv_w (1536x512) and proj_w (512x512) fp32 -> bf16
// =====================================================================
__global__ __launch_bounds__(256)
void wconv_kernel(const float* __restrict__ qw, const float* __restrict__ pw,
                  bf16_t* __restrict__ qwb, bf16_t* __restrict__ pwb)
{
  const int gid = blockIdx.x * 256 + threadIdx.x;   // one float4 each
  const int n1 = NO3 * NC / 4;                      // 196608
  float4 v; bf16x4 o;
  if (gid < n1) {
    v = ((const float4*)qw)[gid];
    o[0] = (bf16_t)v.x; o[1] = (bf16_t)v.y; o[2] = (bf16_t)v.z; o[3] = (bf16_t)v.w;
    ((bf16x4*)qwb)[gid] = o;
  } else {
    int g2 = gid - n1;                              // < 65536
    v = ((const float4*)pw)[g2];
    o[0] = (bf16_t)v.x; o[1] = (bf16_t)v.y; o[2] = (bf16_t)v.z; o[3] = (bf16_t)v.w;
    ((bf16x4*)pwb)[g2] = o;
  }
}

// =====================================================================
// Shared 128x128 (K=512, BK=32) NT main loop: A rows -> D rows, B rows -> D cols.
// LDS layout: row-major (row, k), stride 32 bf16, no pad (global_load_lds constraint).
// =====================================================================
__device__ __forceinline__ void gemm_mainloop(const bf16_t* Ap, const bf16_t* Bp,
                                              bf16_t* sA, bf16_t* sB, f32x4 (&acc)[4][4])
{
  const int tid = threadIdx.x;
  const int wave = tid >> 6, lane = tid & 63;
  const int quad = lane >> 4, l16 = lane & 15;
  const int wm = wave >> 1, wn = wave & 1;
  for (int k0 = 0; k0 < 512; k0 += 32) {
    #pragma unroll
    for (int j = 0; j < 2; ++j) {
      int c = wave * 64 + j * 256 + lane;      // chunk id, 16B each
      int row = c >> 2, ko = (c & 3) * 8;
      lds_load16(sA + (size_t)(wave * 64 + j * 256) * 8, Ap + (size_t)row * 512 + k0 + ko);
      lds_load16(sB + (size_t)(wave * 64 + j * 256) * 8, Bp + (size_t)row * 512 + k0 + ko);
    }
    __syncthreads();
    bf16x8 af[4], bfr[4];
    #pragma unroll
    for (int mi = 0; mi < 4; ++mi)
      af[mi] = *(const bf16x8*)(sA + (wm * 64 + mi * 16 + l16) * 32 + quad * 8);
    #pragma unroll
    for (int ni = 0; ni < 4; ++ni)
      bfr[ni] = *(const bf16x8*)(sB + (wn * 64 + ni * 16 + l16) * 32 + quad * 8);
    #pragma unroll
    for (int mi = 0; mi < 4; ++mi)
      #pragma unroll
      for (int ni = 0; ni < 4; ++ni)
        acc[mi][ni] = __builtin_amdgcn_mfma_f32_16x16x32_bf16(af[mi], bfr[ni], acc[mi][ni], 0, 0, 0);
    __syncthreads();
  }
}

// =====================================================================
// Kernel 3: QKV GEMM.  D[s, o] = xn[b,s,:] . w[o,:]  (M=s=1024, N=o=1536, K=512)
// Epilogue scatters: q,k -> (b,h,s,d) [q scaled by 0.125]; v -> (b,h,d,t) via LDS transpose.
// grid (12, 8, 8) = (o-tile, s-tile, b)
// =====================================================================
__global__ __launch_bounds__(256, 2)
void qkv_gemm(const bf16_t* __restrict__ xn, const bf16_t* __restrict__ w,
              const float* __restrict__ bias,
              bf16_t* __restrict__ qbuf, bf16_t* __restrict__ kbuf, bf16_t* __restrict__ vbuf)
{
  __shared__ __align__(16) bf16_t smem[128 * 136];   // 34816 B; main loop uses first 16 KB
  bf16_t* sA = smem;
  bf16_t* sB = smem + 4096;
  const int tid = threadIdx.x;
  const int wave = tid >> 6, lane = tid & 63;
  const int quad = lane >> 4, l16 = lane & 15;
  const int wm = wave >> 1, wn = wave & 1;
  const int bx = blockIdx.x, by = blockIdx.y, b = blockIdx.z;

  const bf16_t* Ap = xn + ((size_t)b * NHW + by * 128) * NC;  // rows = s
  const bf16_t* Bp = w + (size_t)bx * 128 * NC;               // rows = o
  f32x4 acc[4][4] = {};
  gemm_mainloop(Ap, Bp, sA, sB, acc);

  const int obase = bx * 128 + wn * 64;
  const int sbase = by * 128 + wm * 64;
  float bv[4];
  #pragma unroll
  for (int ni = 0; ni < 4; ++ni) bv[ni] = bias[obase + ni * 16 + l16];

  if (bx < 8) {               // q (bx<4) or k region: o-contiguous layout (b,h,s,d)
    const bool isq = (bx < 4);
    bf16_t* basep = isq ? qbuf : kbuf;
    const float scale = isq ? 0.125f : 1.0f;   // hd^-0.5 folded into q
    #pragma unroll
    for (int ni = 0; ni < 4; ++ni) {
      int o = obase + ni * 16 + l16;
      int hh = (o >> 6) & 7, dd = o & 63;
      bf16_t* dst = basep + ((size_t)(b * NHEAD + hh) * NHW) * NHD + dd;
      #pragma unroll
      for (int mi = 0; mi < 4; ++mi)
        #pragma unroll
        for (int r = 0; r < 4; ++r) {
          int s = sbase + mi * 16 + quad * 4 + r;
          dst[(size_t)s * NHD] = (bf16_t)((acc[mi][ni][r] + bv[ni]) * scale);
        }
    }
  } else {                    // v region: transpose tile via LDS -> (b,h,d,t)
    bf16_t* sC = smem;        // 128 (o) x 136 stride (s)
    __syncthreads();
    #pragma unroll
    for (int ni = 0; ni < 4; ++ni)
      #pragma unroll
      for (int mi = 0; mi < 4; ++mi)
        #pragma unroll
        for (int r = 0; r < 4; ++r)
          sC[(wn * 64 + ni * 16 + l16) * 136 + wm * 64 + mi * 16 + quad * 4 + r] =
              (bf16_t)(acc[mi][ni][r] + bv[ni]);
    __syncthreads();
    int o_local = tid >> 1, shalf = (tid & 1) << 6;
    int ov = (bx - 8) * 128 + o_local;
    int hh = ov >> 6, dd = ov & 63;
    bf16_t* dst = vbuf + ((size_t)(b * NHEAD + hh) * NHD + dd) * NHW + by * 128 + shalf;
    #pragma unroll
    for (int jj = 0; jj < 8; ++jj)
      *(bf16x8*)(dst + jj * 8) = *(const bf16x8*)&sC[o_local * 136 + shalf + jj * 8];
  }
}

// =====================================================================
// Kernel 4: flash attention, transposed-S formulation.
// grid 512 = (qt fastest (8), h, b); 4 waves; wave owns 32 q-rows (2 s-tiles).
// S^T = K.Q^T  (A=K rows t, B=Q rows s)  -> lane's whole frag has s = l16.
// O^T = V^T.P^T via K=16 MFMA: P^T C-layout == B-layout (t = mt*16+quad*4+j),
// so P stays in the producing lane's registers. No P LDS/shuffle traffic.
// =====================================================================
__global__ __launch_bounds__(256, 2)
void attn_kernel(const bf16_t* __restrict__ qbuf, const bf16_t* __restrict__ kbuf,
                 const bf16_t* __restrict__ vbuf, bf16_t* __restrict__ obuf)
{
  __shared__ __align__(16) bf16_t Ks[128 * 72];     // (t, d) pad 64->72
  __shared__ __align__(16) bf16_t Vs[64 * 136];     // (d, t) pad 128->136

  const int tid = threadIdx.x;
  const int wave = tid >> 6, lane = tid & 63;
  const int quad = lane >> 4, l16 = lane & 15;
  const int idx = blockIdx.x;
  const int qt = idx & 7, h = (idx >> 3) & 7, b = idx >> 6;
  const size_t bh = (size_t)b * NHEAD + h;
  const bf16_t* qp = qbuf + (bh * NHW + qt * 128 + wave * 32) * NHD;
  const bf16_t* kp = kbuf + bh * NHW * NHD;
  const bf16_t* vp = vbuf + bh * NHD * NHW;

  // Q B-frags: B[n=s(l16)][k=d(quad*8+j)], per s-tile and per K=32 chunk
  bf16x8 qf[2][2];
  #pragma unroll
  for (int stile = 0; stile < 2; ++stile)
    #pragma unroll
    for (int kc = 0; kc < 2; ++kc)
      qf[stile][kc] = *(const bf16x8*)(qp + (size_t)(stile * 16 + l16) * NHD + kc * 32 + quad * 8);

  float m_i[2] = {-1e30f, -1e30f}, l_i[2] = {0.f, 0.f};
  f32x4 oacc[4][2] = {};   // O^T: [mi over d][stile]

  for (int kt = 0; kt < 8; ++kt) {
    const bf16_t* ksrc = kp + (size_t)kt * 128 * NHD;
    const bf16_t* vsrc = vp + kt * 128;
    #pragma unroll
    for (int j = 0; j < 4; ++j) {              // K tile: 1024 16B chunks
      int c = tid + j * 256;
      int t = c >> 3, doff = (c & 7) * 8;
      *(bf16x8*)&Ks[t * 72 + doff] = *(const bf16x8*)(ksrc + (size_t)t * NHD + doff);
    }
    #pragma unroll
    for (int j = 0; j < 4; ++j) {              // V^T tile: 1024 16B chunks
      int c = tid + j * 256;
      int d = c >> 4, toff = (c & 15) * 8;
      *(bf16x8*)&Vs[d * 136 + toff] = *(const bf16x8*)(vsrc + (size_t)d * NHW + toff);
    }
    __syncthreads();

    // S^T[t][s]: lane (quad,l16) holds t = mt*16 + quad*4 + r, s = l16 (+16*stile)
    f32x4 st[2][8];
    #pragma unroll
    for (int mt = 0; mt < 8; ++mt) {
      bf16x8 ka0 = *(const bf16x8*)&Ks[(mt * 16 + l16) * 72 + quad * 8];
      bf16x8 ka1 = *(const bf16x8*)&Ks[(mt * 16 + l16) * 72 + 32 + quad * 8];
      #pragma unroll
      for (int stile = 0; stile < 2; ++stile) {
        f32x4 z = {};
        z = __builtin_amdgcn_mfma_f32_16x16x32_bf16(ka0, qf[stile][0], z, 0, 0, 0);
        z = __builtin_amdgcn_mfma_f32_16x16x32_bf16(ka1, qf[stile][1], z, 0, 0, 0);
        st[stile][mt] = z;
      }
    }

    // online softmax: all of a lane's values share s -> scalar m/l per stile
    #pragma unroll
    for (int stile = 0; stile < 2; ++stile) {
      float mx = -1e30f;
      #pragma unroll
      for (int mt = 0; mt < 8; ++mt)
        #pragma unroll
        for (int r = 0; r < 4; ++r) mx = fmaxf(mx, st[stile][mt][r]);
      mx = fmaxf(mx, __shfl_xor(mx, 16));
      mx = fmaxf(mx, __shfl_xor(mx, 32));
      float mnew = fmaxf(m_i[stile], mx);
      float alpha = __expf(m_i[stile] - mnew);
      m_i[stile] = mnew;
      float rs = 0.f;
      #pragma unroll
      for (int mt = 0; mt < 8; ++mt)
        #pragma unroll
        for (int r = 0; r < 4; ++r) {
          float p = __expf(st[stile][mt][r] - mnew);
          rs += p;
          st[stile][mt][r] = p;
        }
      rs += __shfl_xor(rs, 16);
      rs += __shfl_xor(rs, 32);
      l_i[stile] = l_i[stile] * alpha + rs;
      #pragma unroll
      for (int mi = 0; mi < 4; ++mi)
        #pragma unroll
        for (int r = 0; r < 4; ++r)
          oacc[mi][stile][r] *= alpha;
    }

    // O^T += V^T . P^T with K=16 per mt tile; P B-frag = lane's own st values.
    #pragma unroll
    for (int mt = 0; mt < 8; ++mt) {
      bf16x4 pb[2];
      #pragma unroll
      for (int stile = 0; stile < 2; ++stile) {
        pb[stile][0] = (bf16_t)st[stile][mt][0];
        pb[stile][1] = (bf16_t)st[stile][mt][1];
        pb[stile][2] = (bf16_t)st[stile][mt][2];
        pb[stile][3] = (bf16_t)st[stile][mt][3];
      }
      #pragma unroll
      for (int mi = 0; mi < 4; ++mi) {
        bf16x4 va = *(const bf16x4*)&Vs[(mi * 16 + l16) * 136 + mt * 16 + quad * 4];
        oacc[mi][0] = mfma16(va, pb[0], oacc[mi][0]);
        oacc[mi][1] = mfma16(va, pb[1], oacc[mi][1]);
      }
    }
    __syncthreads();
  }

  // epilogue: O^T C-layout: row = d = mi*16 + quad*4 + r, col = s = l16
  #pragma unroll
  for (int stile = 0; stile < 2; ++stile) {
    float inv = 1.0f / l_i[stile];
    int s = qt * 128 + wave * 32 + stile * 16 + l16;
    bf16_t* orow = obuf + ((size_t)b * NHW + s) * NC + h * NHD;
    #pragma unroll
    for (int mi = 0; mi < 4; ++mi) {
      __align__(8) bf16_t o4[4];
      #pragma unroll
      for (int r = 0; r < 4; ++r) o4[r] = (bf16_t)(oacc[mi][stile][r] * inv);
      *(bf16x4*)(orow + mi * 16 + quad * 4) = *(const bf16x4*)o4;
    }
  }
}

// =====================================================================
// Kernel 5: proj GEMM + bias + residual. D[co, s] = w[co,:] . ob[b,s,:]
// grid (8, 4, 8) = (s-tile, co-tile, b). fp32 out, coalesced over s.
// =====================================================================
__global__ __launch_bounds__(256, 2)
void proj_gemm(const bf16_t* __restrict__ ob, const bf16_t* __restrict__ w,
               const float* __restrict__ bias, const float* __restrict__ x,
               float* __restrict__ out)
{
  __shared__ __align__(16) bf16_t smem[8192];
  bf16_t* sA = smem;
  bf16_t* sB = smem + 4096;
  const int tid = threadIdx.x;
  const int wave = tid >> 6, lane = tid & 63;
  const int quad = lane >> 4, l16 = lane & 15;
  const int wm = wave >> 1, wn = wave & 1;
  const int bx = blockIdx.x, by = blockIdx.y, b = blockIdx.z;

  const bf16_t* Ap = w + (size_t)by * 128 * NC;               // rows = co
  const bf16_t* Bp = ob + ((size_t)b * NHW + bx * 128) * NC;  // rows = s
  f32x4 acc[4][4] = {};
  gemm_mainloop(Ap, Bp, sA, sB, acc);

  const int cobase = by * 128 + wm * 64;
  const int sbase  = bx * 128 + wn * 64;
  #pragma unroll
  for (int mi = 0; mi < 4; ++mi)
    #pragma unroll
    for (int r = 0; r < 4; ++r) {
      int co = cobase + mi * 16 + quad * 4 + r;
      float pb = bias[co];
      const float* xrow = x + ((size_t)b * NC + co) * NHW;
      float* orow = out + ((size_t)b * NC + co) * NHW;
      #pragma unroll
      for (int ni = 0; ni < 4; ++ni) {
        int s = sbase + ni * 16 + l16;
        orow[s] = acc[mi][ni][r] + pb + xrow[s];
      }
    }
}

// =====================================================================
extern "C" void kernel_launch(void* const* d_in, const int* in_sizes, int n_in,
                              void* d_out, int out_size, void* d_ws, size_t ws_size,
                              hipStream_t stream)
{
  const float* x      = (const float*)d_in[0];
  const float* gn_w   = (const float*)d_in[1];
  const float* gn_b   = (const float*)d_in[2];
  const float* qkv_w  = (const float*)d_in[3];
  const float* qkv_b  = (const float*)d_in[4];
  const float* proj_w = (const float*)d_in[5];
  const float* proj_b = (const float*)d_in[6];
  float* out = (float*)d_out;

  char* ws = (char*)d_ws;
  // xn (B,HW,C) bf16 reused later as attention output obuf (B,HW,C) bf16
  bf16_t* xn   = (bf16_t*)(ws);                       //  8 MiB
  bf16_t* qwb  = (bf16_t*)(ws + 8388608);             //  1.5 MiB (1536x512)
  bf16_t* pwb  = (bf16_t*)(ws + 9961472);             //  0.5 MiB (512x512)
  bf16_t* qbuf = (bf16_t*)(ws + 10485760);            //  8 MiB (b,h,s,d)
  bf16_t* kbuf = (bf16_t*)(ws + 18874368);            //  8 MiB (b,h,s,d)
  bf16_t* vbuf = (bf16_t*)(ws + 27262976);            //  8 MiB (b,h,d,t)
  bf16_t* obuf = xn;                                  // reuse: xn dead after qkv_gemm

  gn_kernel<<<dim3(NB * NG), dim3(256), 0, stream>>>(x, gn_w, gn_b, xn);
  wconv_kernel<<<dim3(1024), dim3(256), 0, stream>>>(qkv_w, proj_w, qwb, pwb);
  qkv_gemm<<<dim3(12, 8, NB), dim3(256), 0, stream>>>(xn, qwb, qkv_b, qbuf, kbuf, vbuf);
  attn_kernel<<<dim3(512), dim3(256), 0, stream>>>(qbuf, kbuf, vbuf, obuf);
  proj_gemm<<<dim3(8, 4, NB), dim3(256), 0, stream>>>(obuf, pwb, proj_b, x, out);
}